// Round 4
// baseline (256.176 us; speedup 1.0000x reference)
//
#include <hip/hip_runtime.h>
#include <cstdint>

#define R_TOT 16384
#define T_NT  2048
#define DD    128
#define HH    512
#define MC_   20
#define BR    32          // rows per block in k3
#define STEPS 64          // 2048 / 32 cols
#define NBLK  (R_TOT / BR)   // 512

// Output layout (floats)
#define MASK_OFF 0
#define LOGP_OFF 16384
#define WORD_OFF 32768
#define CHAR_OFF 49152
#define EMB_OFF  376832          // 49152 + 16384*20
#define LOSS_OFF 2473984         // 376832 + 16384*128

// ws layout (float slots)
#define X_OFF     0              // x f32 [16384][128]
#define HDN_OFF   2097152        // hdn f32 [16384][512]
#define HDNB_OFF  10485760       // hdn bf16 ushort[16384*512]
#define WT_OFF    14680064       // wtgt f32 [2048][128]
#define WTT_OFF   14942208       // wtgtT bf16 ushort[128*2048]
#define W2T_OFF   15073280       // W2T f32 [2048][512]
#define W2TB_OFF  16121856       // W2T bf16 ushort[2048*512]
#define ENT_OFF   16646144       // 512
#define CNT_OFF   16647168       // 512

typedef __attribute__((ext_vector_type(8))) short short8v;
typedef __attribute__((ext_vector_type(4))) float f32x4;
typedef unsigned short ushort_t;

__device__ __forceinline__ ushort_t f2bf(float f) {
    union { float f; unsigned int u; } v; v.f = f;
    unsigned int r = v.u + 0x7FFFu + ((v.u >> 16) & 1u);
    return (ushort_t)(r >> 16);
}

__device__ __forceinline__ void stage16(const ushort_t* gsrc, ushort_t* ldst) {
    __builtin_amdgcn_global_load_lds(
        (const __attribute__((address_space(1))) unsigned int*)gsrc,
        (__attribute__((address_space(3))) unsigned int*)ldst, 16, 0, 0);
}

// ---------------- K1: gather embeddings ----------------
__global__ __launch_bounds__(256) void k1_gather(
    const int* __restrict__ inp_word, const int* __restrict__ tgt_ids,
    const float* __restrict__ W, float* __restrict__ x, float* __restrict__ wtgt)
{
    int row = blockIdx.x * 2 + (threadIdx.x >> 7);
    int d = threadIdx.x & 127;
    if (row < R_TOT) {
        int wsrc = inp_word[row];
        x[(size_t)row * DD + d] = W[(size_t)wsrc * DD + d];
    } else {
        int rr = row - R_TOT;
        if (rr < T_NT) {
            int wsrc = tgt_ids[rr];
            wtgt[(size_t)rr * DD + d] = W[(size_t)wsrc * DD + d];
        }
    }
}

// ---------------- K1b: wtgt [2048][128] -> wtgtT bf16 [128][2048] ----------------
__global__ __launch_bounds__(256) void k1b_wtgtT(
    const float* __restrict__ wtgt, ushort_t* __restrict__ wtgtT)
{
    __shared__ float tile[32][33];
    int tb = blockIdx.x * 32, db = blockIdx.y * 32;
    int lx = threadIdx.x & 31, ly = threadIdx.x >> 5;
    #pragma unroll
    for (int i = 0; i < 32; i += 8)
        tile[ly + i][lx] = wtgt[(size_t)(tb + ly + i) * DD + db + lx];
    __syncthreads();
    #pragma unroll
    for (int i = 0; i < 32; i += 8)
        wtgtT[(size_t)(db + ly + i) * T_NT + tb + lx] = f2bf(tile[lx][ly + i]);
}

// ---------------- K0: W2 [512][2048] -> W2T f32+bf16 [2048][512] ----------------
__global__ __launch_bounds__(256) void k0_w2t(
    const float* __restrict__ W2, float* __restrict__ W2Tf, ushort_t* __restrict__ W2Tb)
{
    __shared__ float tile[32][33];
    int cb = blockIdx.x * 32, kb = blockIdx.y * 32;
    int lx = threadIdx.x & 31, ly = threadIdx.x >> 5;
    #pragma unroll
    for (int i = 0; i < 32; i += 8)
        tile[ly + i][lx] = W2[(size_t)(kb + ly + i) * T_NT + cb + lx];
    __syncthreads();
    #pragma unroll
    for (int i = 0; i < 32; i += 8) {
        int c = cb + ly + i, k = kb + lx;
        float v = tile[lx][ly + i];
        W2Tf[(size_t)c * HH + k] = v;
        W2Tb[(size_t)c * HH + k] = f2bf(v);
    }
}

// ---------------- K2: hdn = relu(x @ W1 + b1), fp32 + bf16 outputs ----------------
__global__ __launch_bounds__(256) void k2_hdn(
    const float* __restrict__ x, const float* __restrict__ W1,
    const float* __restrict__ b1, float* __restrict__ hdn, ushort_t* __restrict__ hdnB)
{
    __shared__ float As[16][64];
    __shared__ float Bs[16][64];
    const int t = threadIdx.x;
    const int bm = blockIdx.x * 64;
    const int bn = blockIdx.y * 64;
    const int tx = t & 15, ty = t >> 4;
    float acc[4][4] = {};
    for (int k0 = 0; k0 < DD; k0 += 16) {
        {
            int m = t >> 2, kq = t & 3;
            float4 v = *(const float4*)(x + (size_t)(bm + m) * DD + k0 + kq * 4);
            As[kq * 4 + 0][m] = v.x; As[kq * 4 + 1][m] = v.y;
            As[kq * 4 + 2][m] = v.z; As[kq * 4 + 3][m] = v.w;
        }
        {
            int k = t >> 4, nq = t & 15;
            *(float4*)(&Bs[k][nq * 4]) =
                *(const float4*)(W1 + (size_t)(k0 + k) * HH + bn + nq * 4);
        }
        __syncthreads();
        #pragma unroll
        for (int k = 0; k < 16; ++k) {
            float a[4], b[4];
            #pragma unroll
            for (int i = 0; i < 4; i++) a[i] = As[k][ty * 4 + i];
            #pragma unroll
            for (int j = 0; j < 4; j++) b[j] = Bs[k][tx * 4 + j];
            #pragma unroll
            for (int i = 0; i < 4; i++)
                #pragma unroll
                for (int j = 0; j < 4; j++)
                    acc[i][j] = fmaf(a[i], b[j], acc[i][j]);
        }
        __syncthreads();
    }
    #pragma unroll
    for (int i = 0; i < 4; i++) {
        int m = bm + ty * 4 + i;
        int n = bn + tx * 4;
        float4 v;
        v.x = fmaxf(acc[i][0] + b1[n + 0], 0.f);
        v.y = fmaxf(acc[i][1] + b1[n + 1], 0.f);
        v.z = fmaxf(acc[i][2] + b1[n + 2], 0.f);
        v.w = fmaxf(acc[i][3] + b1[n + 3], 0.f);
        *(float4*)(hdn + (size_t)m * HH + n) = v;
        ushort4 hb;
        hb.x = f2bf(v.x); hb.y = f2bf(v.y); hb.z = f2bf(v.z); hb.w = f2bf(v.w);
        *(ushort4*)(hdnB + (size_t)m * HH + n) = hb;
    }
}

// ---------------- K3: streaming fused kernel (pipelined) ----------------
// 512 blocks x 32 rows, 4 waves = 2 Mgroups(16 rows) x 2 Cgroups.
// W2T tile staged k-major: granule (kc 0..63, gi 0..31): LDS slot kc*32+gi holds
// W2 col (gi ^ (kc&7)), k-granule kc. Read addr = invariant base +/- compile-time imm.
__global__ __launch_bounds__(256, 2) void k3_fused(
    const ushort_t* __restrict__ hdnB, const float* __restrict__ hdn,
    const ushort_t* __restrict__ W2Tb, const float* __restrict__ W2Tf,
    const float* __restrict__ b2, const float* __restrict__ gumbel,
    const int* __restrict__ inp_word, const int* __restrict__ keyword_table,
    const int* __restrict__ tgt_ids, const int* __restrict__ lut,
    const float* __restrict__ x, const ushort_t* __restrict__ wtgtT,
    float* __restrict__ out, float* __restrict__ entP, float* __restrict__ cntP)
{
    __shared__ ushort_t wS[2 * 16384];       // 2 x 32KB W2T tiles (k-major, swizzled)
    __shared__ float pS[2 * 2 * 16 * 36];    // [Mgrp][parity][16 rows][36]
    __shared__ float statC1[2 * 16 * 8];
    __shared__ int   candS[BR * 2];
    __shared__ float invs2S[BR], entS[BR];
    __shared__ int   mskS[BR];

    const int t = threadIdx.x;
    const int wid = t >> 6, lane = t & 63;
    const int Mgrp = wid >> 1, Cgrp = wid & 1;
    const int lrow = lane & 15, kgrp = lane >> 4;
    const int row0 = blockIdx.x * BR;
    const int rowA = row0 + Mgrp * 16 + lrow;
    const int c_local = Cgrp * 16 + lrow;
    const int dbase = Cgrp * 64 + lrow;

    // ---- A fragments: full K in registers ----
    short8v av[16];
    #pragma unroll
    for (int ks = 0; ks < 16; ++ks)
        av[ks] = *(const short8v*)(hdnB + (size_t)rowA * HH + ks * 32 + kgrp * 8);

    // ---- staging source pointers (tile 0), advanced 32KB/step ----
    const ushort_t* sp[8];
    #pragma unroll
    for (int i = 0; i < 8; ++i) {
        int slot = wid * 512 + i * 64 + lane;
        int kc = slot >> 5, gi = slot & 31;
        int c = gi ^ (kc & 7);
        sp[i] = W2Tb + (size_t)c * HH + kc * 8;
    }

    // ---- LDS read bases (loop-invariant; imm = ks*2048B) ----
    const int inv = kgrp * 256 + ((c_local ^ kgrp) << 3);   // ushort units
    const ushort_t* wbE0 = &wS[inv];
    const ushort_t* wbO0 = &wS[inv ^ 32];
    const ushort_t* wbE1 = wbE0 + 16384;
    const ushort_t* wbO1 = wbO0 + 16384;

    // ---- running pointers for gumbel / b2 / wtgtT ----
    const float* gp0 = gumbel + (size_t)(row0 + Mgrp * 16 + kgrp * 4 + 0) * T_NT + c_local;
    const float* gp1 = gp0 + T_NT;
    const float* gp2 = gp1 + T_NT;
    const float* gp3 = gp2 + T_NT;
    const float* b2p = b2 + c_local;
    const ushort_t* vp0 = wtgtT + (size_t)(dbase + 0)  * T_NT + kgrp * 8;
    const ushort_t* vp1 = wtgtT + (size_t)(dbase + 16) * T_NT + kgrp * 8;
    const ushort_t* vp2 = wtgtT + (size_t)(dbase + 32) * T_NT + kgrp * 8;
    const ushort_t* vp3 = wtgtT + (size_t)(dbase + 48) * T_NT + kgrp * 8;

    // ---- stats ----
    float m_[4], sE_[4], sEl_[4], s2_[4], a1_[4], a2_[4];
    int i1_[4], i2_[4];
    #pragma unroll
    for (int q = 0; q < 4; ++q) {
        m_[q] = -1e30f; sE_[q] = 0.f; sEl_[q] = 0.f; s2_[q] = 0.f;
        a1_[q] = -1e30f; a2_[q] = -1e30f; i1_[q] = 0; i2_[q] = 0;
    }
    f32x4 accpv[4];
    #pragma unroll
    for (int df = 0; df < 4; ++df) accpv[df] = (f32x4){0.f, 0.f, 0.f, 0.f};

    // ---- prologue: stage tile 0 into buf 0 ----
    #pragma unroll
    for (int i = 0; i < 8; ++i) {
        stage16(sp[i], &wS[(wid * 512 + i * 64) * 8]);
        sp[i] += 16384;
    }
    __syncthreads();

    int colv = c_local;

    for (int s = 0; s < STEPS; ++s) {
        const int buf = s & 1;
        // -- prefetch next tile into buf^1 --
        if (s + 1 < STEPS) {
            ushort_t* wdst = &wS[(buf ^ 1) * 16384];
            #pragma unroll
            for (int i = 0; i < 8; ++i) {
                stage16(sp[i], wdst + (wid * 512 + i * 64) * 8);
                sp[i] += 16384;
            }
        }
        // -- early loads --
        float g0 = *gp0, g1 = *gp1, g2 = *gp2, g3 = *gp3;
        gp0 += 32; gp1 += 32; gp2 += 32; gp3 += 32;
        float b2v = *b2p; b2p += 32;
        short8v bvf0 = *(const short8v*)vp0; vp0 += 32;
        short8v bvf1 = *(const short8v*)vp1; vp1 += 32;
        short8v bvf2 = *(const short8v*)vp2; vp2 += 32;
        short8v bvf3 = *(const short8v*)vp3; vp3 += 32;

        // -- S tile: 16 MFMA in 4 independent chains, imm-offset ds_reads --
        const ushort_t* we = buf ? wbE1 : wbE0;
        const ushort_t* wo = buf ? wbO1 : wbO0;
        f32x4 ac0 = (f32x4){0.f,0.f,0.f,0.f}, ac1 = ac0, ac2 = ac0, ac3 = ac0;
        __builtin_amdgcn_s_setprio(1);
        #pragma unroll
        for (int ks = 0; ks < 16; ks += 4) {
            ac0 = __builtin_amdgcn_mfma_f32_16x16x32_bf16(av[ks+0], *(const short8v*)(we + (ks+0)*1024), ac0, 0, 0, 0);
            ac1 = __builtin_amdgcn_mfma_f32_16x16x32_bf16(av[ks+1], *(const short8v*)(wo + (ks+1)*1024), ac1, 0, 0, 0);
            ac2 = __builtin_amdgcn_mfma_f32_16x16x32_bf16(av[ks+2], *(const short8v*)(we + (ks+2)*1024), ac2, 0, 0, 0);
            ac3 = __builtin_amdgcn_mfma_f32_16x16x32_bf16(av[ks+3], *(const short8v*)(wo + (ks+3)*1024), ac3, 0, 0, 0);
        }
        __builtin_amdgcn_s_setprio(0);
        f32x4 acc = (ac0 + ac1) + (ac2 + ac3);

        // -- stats + top2 + P write --
        float* pT = &pS[(Mgrp * 2 + buf) * 576];
        float g4[4] = {g0, g1, g2, g3};
        #pragma unroll
        for (int q = 0; q < 4; ++q) {
            float l = acc[q] + b2v;
            m_[q] = fmaxf(m_[q], l);
            float e1 = __expf(l);
            sE_[q] += e1; sEl_[q] = fmaf(e1, l, sEl_[q]);
            float a = l + g4[q];
            float p = __expf(2.0f * a);
            s2_[q] += p;
            if (a > a1_[q]) { a2_[q] = a1_[q]; i2_[q] = i1_[q]; a1_[q] = a; i1_[q] = colv; }
            else if (a > a2_[q]) { a2_[q] = a; i2_[q] = colv; }
            pT[(kgrp * 4 + q) * 36 + c_local] = p;
        }

        asm volatile("s_waitcnt lgkmcnt(0)" ::: "memory");
        __builtin_amdgcn_s_barrier();
        __builtin_amdgcn_sched_barrier(0);

        // -- PV --
        {
            const float* pr = &pS[(Mgrp * 2 + buf) * 576 + lrow * 36 + kgrp * 8];
            float4 pa = *(const float4*)(pr);
            float4 pb = *(const float4*)(pr + 4);
            short8v pav;
            pav[0] = (short)f2bf(pa.x); pav[1] = (short)f2bf(pa.y);
            pav[2] = (short)f2bf(pa.z); pav[3] = (short)f2bf(pa.w);
            pav[4] = (short)f2bf(pb.x); pav[5] = (short)f2bf(pb.y);
            pav[6] = (short)f2bf(pb.z); pav[7] = (short)f2bf(pb.w);
            __builtin_amdgcn_s_setprio(1);
            accpv[0] = __builtin_amdgcn_mfma_f32_16x16x32_bf16(pav, bvf0, accpv[0], 0, 0, 0);
            accpv[1] = __builtin_amdgcn_mfma_f32_16x16x32_bf16(pav, bvf1, accpv[1], 0, 0, 0);
            accpv[2] = __builtin_amdgcn_mfma_f32_16x16x32_bf16(pav, bvf2, accpv[2], 0, 0, 0);
            accpv[3] = __builtin_amdgcn_mfma_f32_16x16x32_bf16(pav, bvf3, accpv[3], 0, 0, 0);
            __builtin_amdgcn_s_setprio(0);
        }

        // -- end-of-step: prefetch landed + everyone past P reads --
        asm volatile("s_waitcnt vmcnt(0)" ::: "memory");
        __builtin_amdgcn_s_barrier();
        __builtin_amdgcn_sched_barrier(0);
        colv += 32;
    }

    // ---- in-wave reduction over lrow (xor 1,2,4,8) ----
    #pragma unroll
    for (int q = 0; q < 4; ++q) {
        #pragma unroll
        for (int mk = 1; mk < 16; mk <<= 1) {
            m_[q] = fmaxf(m_[q], __shfl_xor(m_[q], mk));
            sE_[q] += __shfl_xor(sE_[q], mk);
            sEl_[q] += __shfl_xor(sEl_[q], mk);
            s2_[q] += __shfl_xor(s2_[q], mk);
            float ob1 = __shfl_xor(a1_[q], mk); int oj1 = __shfl_xor(i1_[q], mk);
            float ob2 = __shfl_xor(a2_[q], mk); int oj2 = __shfl_xor(i2_[q], mk);
            if (ob1 > a1_[q] || (ob1 == a1_[q] && oj1 < i1_[q])) {
                if (a1_[q] > ob2 || (a1_[q] == ob2 && i1_[q] < oj2)) { a2_[q] = a1_[q]; i2_[q] = i1_[q]; }
                else { a2_[q] = ob2; i2_[q] = oj2; }
                a1_[q] = ob1; i1_[q] = oj1;
            } else {
                if (ob1 > a2_[q]) { a2_[q] = ob1; i2_[q] = oj1; }
            }
        }
    }

    // ---- cross-C merge via LDS ----
    if (Cgrp == 1 && lrow == 0) {
        #pragma unroll
        for (int q = 0; q < 4; ++q) {
            int r = kgrp * 4 + q;
            float* st = &statC1[(Mgrp * 16 + r) * 8];
            st[0] = m_[q]; st[1] = sE_[q]; st[2] = sEl_[q]; st[3] = s2_[q];
            st[4] = a1_[q]; st[5] = __int_as_float(i1_[q]);
            st[6] = a2_[q]; st[7] = __int_as_float(i2_[q]);
        }
    }
    __syncthreads();

    if (Cgrp == 0) {
        #pragma unroll
        for (int q = 0; q < 4; ++q) {
            int r = kgrp * 4 + q;
            const float* st = &statC1[(Mgrp * 16 + r) * 8];
            float bm = st[0], bsE = st[1], bsEl = st[2], bs2 = st[3];
            float b1v = st[4]; int j1 = __float_as_int(st[5]);
            float b2c = st[6]; int j2 = __float_as_int(st[7]);
            float m = fmaxf(m_[q], bm);
            float sE = sE_[q] + bsE, sEl = sEl_[q] + bsEl, s2 = s2_[q] + bs2;
            float a1 = a1_[q], a2 = a2_[q]; int i1 = i1_[q], i2 = i2_[q];
            if (b1v > a1 || (b1v == a1 && j1 < i1)) {
                if (a1 > b2c || (a1 == b2c && i1 < j2)) { a2 = a1; i2 = i1; }
                else { a2 = b2c; i2 = j2; }
                a1 = b1v; i1 = j1;
            } else {
                if (b1v > a2) { a2 = b1v; i2 = j1; }
            }
            if (lrow == 0) {
                int grow = row0 + Mgrp * 16 + r;
                int w_in = inp_word[grow];
                int msk = keyword_table[w_in] != 0;
                out[MASK_OFF + grow] = msk ? 1.0f : 0.0f;
                out[LOGP_OFF + grow] = msk ? m : 0.0f;
                invs2S[Mgrp * 16 + r] = 1.0f / s2;
                mskS[Mgrp * 16 + r] = msk;
                entS[Mgrp * 16 + r] = msk ? (__logf(sE) - sEl / sE) : 0.0f;
                candS[(Mgrp * 16 + r) * 2 + 0] = i1;
                candS[(Mgrp * 16 + r) * 2 + 1] = i2;
            }
        }
    }
    __syncthreads();

    // ---- x_emb epilogue: scale + select + store ----
    #pragma unroll
    for (int df = 0; df < 4; ++df) {
        #pragma unroll
        for (int q = 0; q < 4; ++q) {
            int rl = Mgrp * 16 + kgrp * 4 + q;
            int grow = row0 + rl;
            int d = dbase + df * 16;
            float val = accpv[df][q] * invs2S[rl];
            if (!mskS[rl]) val = x[(size_t)grow * DD + d];
            out[EMB_OFF + (size_t)grow * DD + d] = val;
        }
    }

    // ---- repair + word/char outputs ----
    for (int rr = wid * 8; rr < wid * 8 + 8; ++rr) {
        int grow = row0 + rr;
        int i1 = candS[rr * 2 + 0], i2 = candS[rr * 2 + 1];
        const float* hrow = hdn + (size_t)grow * HH;
        float4 h0 = *(const float4*)(hrow + lane * 8);
        float4 h1 = *(const float4*)(hrow + lane * 8 + 4);
        float v1, v2;
        {
            const float* wrow = W2Tf + (size_t)i1 * HH;
            float4 w0 = *(const float4*)(wrow + lane * 8);
            float4 w1 = *(const float4*)(wrow + lane * 8 + 4);
            float sdot = h0.x*w0.x + h0.y*w0.y + h0.z*w0.z + h0.w*w0.w
                       + h1.x*w1.x + h1.y*w1.y + h1.z*w1.z + h1.w*w1.w;
            #pragma unroll
            for (int mk = 1; mk < 64; mk <<= 1) sdot += __shfl_xor(sdot, mk);
            v1 = sdot + b2[i1] + gumbel[(size_t)grow * T_NT + i1];
        }
        {
            const float* wrow = W2Tf + (size_t)i2 * HH;
            float4 w0 = *(const float4*)(wrow + lane * 8);
            float4 w1 = *(const float4*)(wrow + lane * 8 + 4);
            float sdot = h0.x*w0.x + h0.y*w0.y + h0.z*w0.z + h0.w*w0.w
                       + h1.x*w1.x + h1.y*w1.y + h1.z*w1.z + h1.w*w1.w;
            #pragma unroll
            for (int mk = 1; mk < 64; mk <<= 1) sdot += __shfl_xor(sdot, mk);
            v2 = sdot + b2[i2] + gumbel[(size_t)grow * T_NT + i2];
        }
        int ibest = (v2 > v1 || (v2 == v1 && i2 < i1)) ? i2 : i1;
        int w_in = inp_word[grow];
        int msk = mskS[rr];
        int word = msk ? tgt_ids[ibest] : w_in;
        if (lane == 0) out[WORD_OFF + grow] = (float)word;
        if (lane < MC_)
            out[CHAR_OFF + (size_t)grow * MC_ + lane] = (float)lut[(size_t)word * MC_ + lane];
    }

    if (t == 0) {
        float es = 0.f; int cs = 0;
        #pragma unroll
        for (int r = 0; r < BR; r++) { es += entS[r]; cs += mskS[r]; }
        entP[blockIdx.x] = es;
        cntP[blockIdx.x] = (float)cs;
    }
}

// ---------------- K4: final loss reduction ----------------
__global__ __launch_bounds__(256) void k4_loss(
    const float* __restrict__ entP, const float* __restrict__ cntP, float* __restrict__ out)
{
    __shared__ float sE[256], sC[256];
    int t = threadIdx.x;
    float e = 0.f, c = 0.f;
    for (int i = t; i < NBLK; i += 256) { e += entP[i]; c += cntP[i]; }
    sE[t] = e; sC[t] = c;
    __syncthreads();
    for (int s = 128; s > 0; s >>= 1) {
        if (t < s) { sE[t] += sE[t + s]; sC[t] += sC[t + s]; }
        __syncthreads();
    }
    if (t == 0) {
        float ns = fmaxf(sC[0], 1.0f);
        out[LOSS_OFF] = 0.03f * sE[0] / ns;
    }
}

// ---------------- launch ----------------
extern "C" void kernel_launch(void* const* d_in, const int* in_sizes, int n_in,
                              void* d_out, int out_size, void* d_ws, size_t ws_size,
                              hipStream_t stream) {
    const int* inp_word = (const int*)d_in[0];
    const int* keyword_table = (const int*)d_in[3];
    const int* tgt_ids = (const int*)d_in[4];
    const int* lut = (const int*)d_in[5];
    const float* gumbel = (const float*)d_in[6];
    const float* W = (const float*)d_in[7];
    const float* W1 = (const float*)d_in[8];
    const float* b1 = (const float*)d_in[9];
    const float* W2 = (const float*)d_in[10];
    const float* b2 = (const float*)d_in[11];
    float* out = (float*)d_out;

    float* wsf = (float*)d_ws;
    float* x = wsf + X_OFF;
    float* hdn = wsf + HDN_OFF;
    ushort_t* hdnB = (ushort_t*)(wsf + HDNB_OFF);
    float* wtgt = wsf + WT_OFF;
    ushort_t* wtgtT = (ushort_t*)(wsf + WTT_OFF);
    float* W2Tf = wsf + W2T_OFF;
    ushort_t* W2Tb = (ushort_t*)(wsf + W2TB_OFF);
    float* entP = wsf + ENT_OFF;
    float* cntP = wsf + CNT_OFF;

    k1_gather<<<(R_TOT + T_NT) / 2, 256, 0, stream>>>(inp_word, tgt_ids, W, x, wtgt);
    k1b_wtgtT<<<dim3(T_NT / 32, DD / 32), 256, 0, stream>>>(wtgt, wtgtT);
    k0_w2t<<<dim3(T_NT / 32, HH / 32), 256, 0, stream>>>(W2, W2Tf, W2Tb);
    k2_hdn<<<dim3(R_TOT / 64, HH / 64), 256, 0, stream>>>(x, W1, b1, hdn, hdnB);
    k3_fused<<<NBLK, 256, 0, stream>>>(hdnB, hdn, W2Tb, W2Tf, b2, gumbel,
                                       inp_word, keyword_table, tgt_ids, lut,
                                       x, wtgtT, out, entP, cntP);
    k4_loss<<<1, 256, 0, stream>>>(entP, cntP, out);
}